// Round 2
// baseline (308.774 us; speedup 1.0000x reference)
//
#include <hip/hip_runtime.h>
#include <hip/hip_bf16.h>

typedef __bf16 bf16x8 __attribute__((ext_vector_type(8)));
typedef float f32x16 __attribute__((ext_vector_type(16)));
typedef unsigned int u32;
typedef unsigned short u16;
typedef u32 u32x4 __attribute__((ext_vector_type(4)));

static constexpr int Nn  = 2048;
static constexpr int Hh  = 8;
static constexpr int DIN = 129;   // in_features = D_IN+1
static constexpr int DO  = 64;    // D_OUT
static constexpr int QP  = 80;    // padded q/k width (65 -> 80)
static constexpr int VR  = 96;    // padded V^T rows (65 -> 96)
static constexpr int AMB = 65;    // ambient dim

#define DEV static __device__ __forceinline__

DEV u16 f2bf(float f) {
  union { __bf16 h; u16 u; } c;
  c.h = (__bf16)f;
  return c.u;
}
DEV u32 pack2(float a, float b) {
  return (u32)f2bf(a) | ((u32)f2bf(b) << 16);
}

// ---------------------------------------------------------------------------
// Projection: s = x @ W[h] + b, lift to hyperboloid, store
//   Qb: [bh][n][80] bf16 = alpha * [qs(64), q0, 0*15]
//   Kb: [bh][n][80] bf16 = [ks(64), -(k0-1), 0*15]   (time centered: softmax-invariant shift)
//   Vt: [bh][96][n] bf16 = rows 0-63 vs, row 64 v0, rows 65-95 zero (transposed)
// ---------------------------------------------------------------------------
__global__ __launch_bounds__(64) void proj_k(
    const float* __restrict__ x,
    const float* __restrict__ Wq, const float* __restrict__ Wk, const float* __restrict__ Wv,
    const float* __restrict__ bq, const float* __restrict__ bk, const float* __restrict__ bv,
    const float* __restrict__ scale_p,
    u16* __restrict__ Qb, u16* __restrict__ Kb, u16* __restrict__ Vt) {
  __shared__ u16 xt[32][152];   // 32 rows x K(144 used), bf16
  __shared__ u16 wt[64][152];   // W^T: [d][k]

  const int l  = threadIdx.x;          // 0..63
  const int rt = blockIdx.x;           // row tile (32 rows of b*n)
  const int z  = blockIdx.y;           // 0..23
  const int T  = z >> 3, h = z & 7;    // tensor (0=Q,1=K,2=V), head
  const float* W    = (T == 0 ? Wq : (T == 1 ? Wk : Wv)) + (size_t)h * DIN * DO;
  const float* bias = (T == 0 ? bq : (T == 1 ? bk : bv)) + h * DO;

  const int row0 = rt * 32;
  for (int r = 0; r < 32; ++r) {
    const float* xr = x + (size_t)(row0 + r) * DIN;
    xt[r][l]      = f2bf(xr[l]);
    xt[r][64 + l] = f2bf(xr[64 + l]);
    if (l == 0) xt[r][128] = f2bf(xr[128]);
    if (l < 16) xt[r][129 + l] = 0;    // zero pad k = 129..144
  }
  for (int i = 0; i < DIN; ++i) wt[l][i] = f2bf(W[(size_t)i * DO + l]);
  for (int i = DIN; i < 144; ++i) wt[l][i] = 0;
  __syncthreads();

  const int lo = l & 31, hi = l >> 5;
  f32x16 acc0 = {}, acc1 = {};
#pragma unroll
  for (int s = 0; s < 9; ++s) {
    bf16x8 a  = *(const bf16x8*)&xt[lo][16 * s + 8 * hi];
    bf16x8 b0 = *(const bf16x8*)&wt[lo][16 * s + 8 * hi];
    bf16x8 b1 = *(const bf16x8*)&wt[32 + lo][16 * s + 8 * hi];
    acc0 = __builtin_amdgcn_mfma_f32_32x32x16_bf16(a, b0, acc0, 0, 0, 0);
    acc1 = __builtin_amdgcn_mfma_f32_32x32x16_bf16(a, b1, acc1, 0, 0, 0);
  }
  const float b0v = bias[lo], b1v = bias[32 + lo];
  const float alpha = 2.0f / (scale_p[0] + 1e-7f);

#pragma unroll
  for (int r = 0; r < 16; ++r) {
    const float s0 = acc0[r] + b0v;
    const float s1 = acc1[r] + b1v;
    float part = s0 * s0 + s1 * s1;
#pragma unroll
    for (int m = 1; m < 32; m <<= 1) part += __shfl_xor(part, m);
    const float time = sqrtf(1.0f + part);     // 1/C_ATTN = 1
    const int dr   = (r & 3) + 8 * (r >> 2) + 4 * hi;  // output row within tile
    const int rowg = row0 + dr;
    const int b = rowg >> 11, n = rowg & 2047;
    const int bh = b * 8 + h;
    if (T == 0) {
      u16* q = Qb + ((size_t)bh * Nn + n) * QP;
      q[lo]      = f2bf(alpha * s0);
      q[32 + lo] = f2bf(alpha * s1);
      if (lo == 0)  q[64] = f2bf(alpha * time);
      if (lo < 15)  q[65 + lo] = 0;
    } else if (T == 1) {
      u16* k = Kb + ((size_t)bh * Nn + n) * QP;
      k[lo]      = f2bf(s0);
      k[32 + lo] = f2bf(s1);
      if (lo == 0)  k[64] = f2bf(-(time - 1.0f));  // centered time, softmax-invariant
      if (lo < 15)  k[65 + lo] = 0;
    } else {
      u16* v = Vt + (size_t)bh * VR * Nn;
      v[(size_t)lo * Nn + n]        = f2bf(s0);
      v[(size_t)(32 + lo) * Nn + n] = f2bf(s1);
      if (lo == 0) v[(size_t)64 * Nn + n] = f2bf(time);
      if (lo > 0)  v[(size_t)(64 + lo) * Nn + n] = 0;  // zero pad rows 65..95
    }
  }
}

// ---------------------------------------------------------------------------
// Flash attention, 1 wave = 32 q-rows, swapped QK^T (mfma(K,Q)) so each lane
// owns one q-column; online softmax in registers; PV = mfma(V^T, P^T) -> O^T.
// Writes per-head Lorentz-normalized mid^T: [bh][65][n] fp32.
// ---------------------------------------------------------------------------
__global__ __launch_bounds__(256) void attn_k(
    const u16* __restrict__ Qb, const u16* __restrict__ Kb,
    const u16* __restrict__ Vt, float* __restrict__ midT) {
  const int tid  = threadIdx.x;
  const int w    = tid >> 6, lane = tid & 63;
  const int lo   = lane & 31, hi = lane >> 5;
  const int bh   = blockIdx.y;
  const int qbase = blockIdx.x * 128 + w * 32;

  // Q fragments (loop-invariant): B-operand of mfma(K,Q): lane -> q = qbase+lo
  const u16* qrow = Qb + ((size_t)bh * Nn + qbase + lo) * QP;
  bf16x8 qf[5];
#pragma unroll
  for (int s = 0; s < 5; ++s) qf[s] = *(const bf16x8*)&qrow[16 * s + 8 * hi];

  f32x16 o0 = {}, o1 = {}, o2 = {};   // O^T rows d = 0..31, 32..63, 64..95
  float mrun = -3.0e38f;
  const u16* kb_p = Kb + (size_t)bh * Nn * QP;
  const u16* vb_p = Vt + (size_t)bh * VR * Nn;

  for (int kb = 0; kb < Nn; kb += 32) {
    // QK^T: D[key][q], 32 keys x 32 q
    const u16* krow = kb_p + (size_t)(kb + lo) * QP;
    f32x16 sc = {};
#pragma unroll
    for (int s = 0; s < 5; ++s) {
      bf16x8 kf = *(const bf16x8*)&krow[16 * s + 8 * hi];
      sc = __builtin_amdgcn_mfma_f32_32x32x16_bf16(kf, qf[s], sc, 0, 0, 0);
    }
    // online softmax (keys live in regs + partner lane l^32)
    float mt = sc[0];
#pragma unroll
    for (int r = 1; r < 16; ++r) mt = fmaxf(mt, sc[r]);
    mt = fmaxf(mt, __shfl_xor(mt, 32));
    const float mnew = fmaxf(mrun, mt);
    const float f = __expf(mrun - mnew);
    mrun = mnew;
    float p[16];
#pragma unroll
    for (int r = 0; r < 16; ++r) p[r] = __expf(sc[r] - mnew);
#pragma unroll
    for (int r = 0; r < 16; ++r) { o0[r] *= f; o1[r] *= f; o2[r] *= f; }

    // P -> bf16 B-fragments (2 k-steps of 16 keys). Own keys per (r,hi) are
    // crow = (r&3)+8*(r>>2)+4*hi; fragment needs k = 8*hi + j contiguous,
    // assembled from own + partner(l^32) packed words.
    u32 wA[4], wB[4], XA[4], XB[4];
#pragma unroll
    for (int j = 0; j < 4; ++j) {
      wA[j] = pack2(p[2 * j], p[2 * j + 1]);
      wB[j] = pack2(p[8 + 2 * j], p[8 + 2 * j + 1]);
    }
#pragma unroll
    for (int j = 0; j < 4; ++j) {
      XA[j] = (u32)__shfl_xor((int)wA[j], 32);
      XB[j] = (u32)__shfl_xor((int)wB[j], 32);
    }
    u32x4 ua, ub;
    if (hi == 0) {
      ua = (u32x4){wA[0], wA[1], XA[0], XA[1]};
      ub = (u32x4){wB[0], wB[1], XB[0], XB[1]};
    } else {
      ua = (u32x4){XA[2], XA[3], wA[2], wA[3]};
      ub = (u32x4){XB[2], XB[3], wB[2], wB[3]};
    }
    union { u32x4 u; bf16x8 b; } ca, cb;
    ca.u = ua; cb.u = ub;
    const bf16x8 fA = ca.b;   // keys kb+0..15
    const bf16x8 fB = cb.b;   // keys kb+16..31

    // PV: O^T[d][q] += V^T[d][key] * P^T[key][q]
#pragma unroll
    for (int t = 0; t < 3; ++t) {
      const u16* vr = vb_p + (size_t)(32 * t + lo) * Nn + kb;
      bf16x8 va = *(const bf16x8*)&vr[8 * hi];
      bf16x8 vb = *(const bf16x8*)&vr[16 + 8 * hi];
      f32x16& ot = (t == 0 ? o0 : (t == 1 ? o1 : o2));
      ot = __builtin_amdgcn_mfma_f32_32x32x16_bf16(va, fA, ot, 0, 0, 0);
      ot = __builtin_amdgcn_mfma_f32_32x32x16_bf16(vb, fB, ot, 0, 0, 0);
    }
  }

  // Lorentz normalize per q (scale-invariant: softmax denominator skipped)
  float part = 0.f;
#pragma unroll
  for (int r = 0; r < 16; ++r)
    part += o0[r] * o0[r] + o1[r] * o1[r] + o2[r] * o2[r];
  if (hi == 0) part -= 2.0f * o2[0] * o2[0];   // d=64 is time: net -time^2
  part += __shfl_xor(part, 32);                // part = lor = ||s||^2 - t^2
  const float inv = rsqrtf(fmaxf(-part, 1e-7f));
  const int q = qbase + lo;
  float* mo = midT + (size_t)bh * AMB * Nn;
#pragma unroll
  for (int r = 0; r < 16; ++r) {
    const int dr = (r & 3) + 8 * (r >> 2) + 4 * hi;
    mo[(size_t)dr * Nn + q]        = o0[r] * inv;
    mo[(size_t)(32 + dr) * Nn + q] = o1[r] * inv;
  }
  if (hi == 0) mo[(size_t)64 * Nn + q] = o2[0] * inv;
}

// ---------------------------------------------------------------------------
// Head-sum (mean absorbed by normalize), normalize, re-lift (C_ATTN=C_OUT=1)
// ---------------------------------------------------------------------------
__global__ __launch_bounds__(256) void final_k(const float* __restrict__ midT,
                                               float* __restrict__ out) {
  const int g = blockIdx.x * 256 + threadIdx.x;   // 0..8191 = b*2048+n
  const int b = g >> 11, n = g & 2047;
  float sum[65];
#pragma unroll
  for (int d = 0; d < 65; ++d) sum[d] = 0.f;
  for (int h = 0; h < 8; ++h) {
    const float* m = midT + (size_t)(b * 8 + h) * AMB * Nn + n;
#pragma unroll
    for (int d = 0; d < 65; ++d) sum[d] += m[(size_t)d * Nn];
  }
  float ss = 0.f;
#pragma unroll
  for (int d = 0; d < 64; ++d) ss += sum[d] * sum[d];
  const float tm  = sum[64];
  const float inv = rsqrtf(fmaxf(tm * tm - ss, 1e-7f));
  const float ssp = ss * inv * inv;               // ||spatial_out||^2
  float* o = out + (size_t)g * 65;
  o[0] = sqrtf(1.0f + ssp);                       // re-lift, 1/C_OUT = 1
#pragma unroll
  for (int d = 0; d < 64; ++d) o[1 + d] = sum[d] * inv;
}

// ---------------------------------------------------------------------------
extern "C" void kernel_launch(void* const* d_in, const int* in_sizes, int n_in,
                              void* d_out, int out_size, void* d_ws, size_t ws_size,
                              hipStream_t stream) {
  (void)in_sizes; (void)n_in; (void)out_size; (void)ws_size;
  const float* x  = (const float*)d_in[0];
  const float* Wq = (const float*)d_in[1];
  const float* Wk = (const float*)d_in[2];
  const float* Wv = (const float*)d_in[3];
  const float* bq = (const float*)d_in[4];
  const float* bk = (const float*)d_in[5];
  const float* bv = (const float*)d_in[6];
  const float* sc = (const float*)d_in[7];
  // d_in[8] = attn_bias: uniform additive score offset -> softmax-invariant.

  char* ws = (char*)d_ws;
  u16*   Qb   = (u16*)(ws);                    // 4*8*2048*80*2 = 10,485,760 B
  u16*   Kb   = (u16*)(ws + 10485760);         // same size
  u16*   Vt   = (u16*)(ws + 20971520);         // 4*8*96*2048*2 = 12,582,912 B
  float* midT = (float*)(ws + 33554432);       // 4*8*65*2048*4 = 17,039,360 B
  float* out  = (float*)d_out;

  hipLaunchKernelGGL(proj_k, dim3(256, 24), dim3(64), 0, stream,
                     x, Wq, Wk, Wv, bq, bk, bv, sc, Qb, Kb, Vt);
  hipLaunchKernelGGL(attn_k, dim3(16, 32), dim3(256), 0, stream, Qb, Kb, Vt, midT);
  hipLaunchKernelGGL(final_k, dim3(32), dim3(256), 0, stream, midT, out);
}

// Round 3
// 305.458 us; speedup vs baseline: 1.0109x; 1.0109x over previous
//
#include <hip/hip_runtime.h>
#include <hip/hip_bf16.h>

typedef __bf16 bf16x8 __attribute__((ext_vector_type(8)));
typedef float f32x16 __attribute__((ext_vector_type(16)));
typedef unsigned int u32;
typedef unsigned short u16;
typedef u32 u32x4 __attribute__((ext_vector_type(4)));

static constexpr int Nn  = 2048;
static constexpr int DIN = 129;   // in_features = D_IN+1
static constexpr int DO  = 64;    // D_OUT
static constexpr int QP  = 80;    // padded q/k width (65 -> 80)
static constexpr int VR  = 96;    // padded V^T rows (65 -> 96)
static constexpr int AMB = 65;    // ambient dim
static constexpr float LOG2E = 1.4426950408889634f;

#define DEV static __device__ __forceinline__

DEV u16 f2bf(float f) {
  union { __bf16 h; u16 u; } c;
  c.h = (__bf16)f;
  return c.u;
}
DEV float bf2f(u16 u) {
  union { float f; u32 u; } c;
  c.u = ((u32)u) << 16;
  return c.f;
}
DEV u32 pack2(float a, float b) {
  return (u32)f2bf(a) | ((u32)f2bf(b) << 16);
}

template <bool BF> struct PSel { typedef float T; };
template <> struct PSel<true> { typedef u16 T; };
DEV void pstore(float* p, float v) { *p = v; }
DEV void pstore(u16* p, float v) { *p = f2bf(v); }
DEV float pload(const float* p) { return *p; }
DEV float pload(const u16* p) { return bf2f(*p); }

// ---------------------------------------------------------------------------
// Projection: s = x @ W[h] + b, lift to hyperboloid (C_ATTN=1), store
//   Qb: [bh][n][80] bf16 = alpha' * [qs(64), q0], alpha' = 2*log2e/(scale+eps)
//   Kb: [bh][n][80] bf16 = [ks(64), -(k0-1)]     (centered time: softmax-inv)
//   Vt: [bh][96][n] bf16 = rows 0-63 vs, row 64 v0, rows 65-95 zero
// 4 waves/block: W^T staged once in LDS (coalesced), one 32-row tile per wave.
// ---------------------------------------------------------------------------
__global__ __launch_bounds__(256) void proj_k(
    const float* __restrict__ x,
    const float* __restrict__ Wq, const float* __restrict__ Wk, const float* __restrict__ Wv,
    const float* __restrict__ bq, const float* __restrict__ bk, const float* __restrict__ bv,
    const float* __restrict__ scale_p,
    u16* __restrict__ Qb, u16* __restrict__ Kb, u16* __restrict__ Vt) {
  __shared__ u16 wt[64][152];       // W^T: [d][k]
  __shared__ u16 xt[4][32][152];    // per-wave x tile

  const int tid = threadIdx.x;
  const int wid = tid >> 6, l = tid & 63;
  const int z = blockIdx.y;            // 0..23
  const int T = z >> 3, h = z & 7;     // tensor (0=Q,1=K,2=V), head
  const float* W    = (T == 0 ? Wq : (T == 1 ? Wk : Wv)) + (size_t)h * DIN * DO;
  const float* bias = (T == 0 ? bq : (T == 1 ? bk : bv)) + h * DO;

  // cooperative W^T load: consecutive tid -> consecutive d -> coalesced
  {
    const int d = tid & 63, kk = tid >> 6;
    for (int k = kk; k < 144; k += 4)
      wt[d][k] = (k < DIN) ? f2bf(W[(size_t)k * DO + d]) : (u16)0;
  }
  const int row0 = (blockIdx.x * 4 + wid) * 32;
  for (int r = 0; r < 32; ++r) {
    const float* xr = x + (size_t)(row0 + r) * DIN;
    xt[wid][r][l]      = f2bf(xr[l]);
    xt[wid][r][64 + l] = f2bf(xr[64 + l]);
    if (l == 0) xt[wid][r][128] = f2bf(xr[128]);
    if (l < 15) xt[wid][r][129 + l] = 0;   // zero pad k = 129..143
  }
  __syncthreads();

  const int lo = l & 31, hi = l >> 5;
  f32x16 acc0 = {}, acc1 = {};
#pragma unroll
  for (int s = 0; s < 9; ++s) {
    bf16x8 a  = *(const bf16x8*)&xt[wid][lo][16 * s + 8 * hi];
    bf16x8 b0 = *(const bf16x8*)&wt[lo][16 * s + 8 * hi];
    bf16x8 b1 = *(const bf16x8*)&wt[32 + lo][16 * s + 8 * hi];
    acc0 = __builtin_amdgcn_mfma_f32_32x32x16_bf16(a, b0, acc0, 0, 0, 0);
    acc1 = __builtin_amdgcn_mfma_f32_32x32x16_bf16(a, b1, acc1, 0, 0, 0);
  }
  const float b0v = bias[lo], b1v = bias[32 + lo];
  const float alpha = 2.0f * LOG2E / (scale_p[0] + 1e-7f);

#pragma unroll
  for (int r = 0; r < 16; ++r) {
    const float s0 = acc0[r] + b0v;
    const float s1 = acc1[r] + b1v;
    float part = s0 * s0 + s1 * s1;
#pragma unroll
    for (int m = 1; m < 32; m <<= 1) part += __shfl_xor(part, m);
    const float time = sqrtf(1.0f + part);     // 1/C_ATTN = 1
    const int dr   = (r & 3) + 8 * (r >> 2) + 4 * hi;
    const int rowg = row0 + dr;
    const int b = rowg >> 11, n = rowg & 2047;
    const int bh = b * 8 + h;
    if (T == 0) {
      u16* q = Qb + ((size_t)bh * Nn + n) * QP;
      q[lo]      = f2bf(alpha * s0);
      q[32 + lo] = f2bf(alpha * s1);
      if (lo == 0)  q[64] = f2bf(alpha * time);
      if (lo < 15)  q[65 + lo] = 0;
    } else if (T == 1) {
      u16* k = Kb + ((size_t)bh * Nn + n) * QP;
      k[lo]      = f2bf(s0);
      k[32 + lo] = f2bf(s1);
      if (lo == 0)  k[64] = f2bf(-(time - 1.0f));
      if (lo < 15)  k[65 + lo] = 0;
    } else {
      u16* v = Vt + (size_t)bh * VR * Nn;
      v[(size_t)lo * Nn + n]        = f2bf(s0);
      v[(size_t)(32 + lo) * Nn + n] = f2bf(s1);
      if (lo == 0) v[(size_t)64 * Nn + n] = f2bf(time);
      if (lo > 0)  v[(size_t)(64 + lo) * Nn + n] = 0;
    }
  }
}

// ---------------------------------------------------------------------------
// Attention (no-max softmax: scores bounded, exp2 direct, normalize is
// scale-invariant -> no denominator, no rescale, no cross-tile state).
// 1 wave = 32 q, swapped QK^T; K-split over blockIdx.z; writes raw partial
// O^T sums: part[bh][s][65][n].
// ---------------------------------------------------------------------------
template <bool BF>
__global__ __launch_bounds__(256, 4) void attn_k(
    const u16* __restrict__ Qb, const u16* __restrict__ Kb,
    const u16* __restrict__ Vt, void* __restrict__ partv) {
  typedef typename PSel<BF>::T PT;
  PT* part = (PT*)partv;
  const int tid  = threadIdx.x;
  const int w    = tid >> 6, lane = tid & 63;
  const int lo   = lane & 31, hi = lane >> 5;
  const int bh   = blockIdx.y;
  const int sidx = blockIdx.z;
  const int qbase = blockIdx.x * 128 + w * 32;

  const u16* qrow = Qb + ((size_t)bh * Nn + qbase + lo) * QP;
  bf16x8 qf[5];
#pragma unroll
  for (int s = 0; s < 5; ++s) qf[s] = *(const bf16x8*)&qrow[16 * s + 8 * hi];

  f32x16 o0 = {}, o1 = {}, o2 = {};   // O^T rows d = 0..31, 32..63, 64..95
  const u16* kb_p = Kb + (size_t)bh * Nn * QP;
  const u16* vb_p = Vt + (size_t)bh * VR * Nn;
  const int k0i = sidx * (Nn / 2), k1i = k0i + (Nn / 2);

  for (int kb = k0i; kb < k1i; kb += 32) {
    // QK^T: D[key][q]
    const u16* krow = kb_p + (size_t)(kb + lo) * QP;
    f32x16 sc = {};
#pragma unroll
    for (int s = 0; s < 5; ++s) {
      bf16x8 kf = *(const bf16x8*)&krow[16 * s + 8 * hi];
      sc = __builtin_amdgcn_mfma_f32_32x32x16_bf16(kf, qf[s], sc, 0, 0, 0);
    }
    // p = 2^score (log2e folded into Q's alpha); no max, no denominator
    float p[16];
#pragma unroll
    for (int r = 0; r < 16; ++r) p[r] = exp2f(sc[r]);

    // P -> bf16 B-fragments. Own keys: crow(r,hi) = (r&3)+8*(r>>2)+4*hi.
    // Fragment needs keys k = 8*hi + j; partner (lane^32) holds the other 8.
    u32 wA[4], wB[4];
#pragma unroll
    for (int j = 0; j < 4; ++j) {
      wA[j] = pack2(p[2 * j], p[2 * j + 1]);
      wB[j] = pack2(p[8 + 2 * j], p[8 + 2 * j + 1]);
    }
    // send-side select: exchange only the 2 words the partner needs (4 shfls)
    const u32 sA0 = hi ? wA[0] : wA[2], sA1 = hi ? wA[1] : wA[3];
    const u32 sB0 = hi ? wB[0] : wB[2], sB1 = hi ? wB[1] : wB[3];
    const u32 rA0 = (u32)__shfl_xor((int)sA0, 32);
    const u32 rA1 = (u32)__shfl_xor((int)sA1, 32);
    const u32 rB0 = (u32)__shfl_xor((int)sB0, 32);
    const u32 rB1 = (u32)__shfl_xor((int)sB1, 32);
    u32x4 ua = hi ? (u32x4){rA0, rA1, wA[2], wA[3]}
                  : (u32x4){wA[0], wA[1], rA0, rA1};
    u32x4 ub = hi ? (u32x4){rB0, rB1, wB[2], wB[3]}
                  : (u32x4){wB[0], wB[1], rB0, rB1};
    union { u32x4 u; bf16x8 b; } ca, cb;
    ca.u = ua; cb.u = ub;
    const bf16x8 fA = ca.b;   // keys kb+0..15
    const bf16x8 fB = cb.b;   // keys kb+16..31

    // PV: O^T[d][q] += V^T[d][key] * P^T[key][q]
#pragma unroll
    for (int t = 0; t < 3; ++t) {
      const u16* vr = vb_p + (size_t)(32 * t + lo) * Nn + kb;
      bf16x8 va = *(const bf16x8*)&vr[8 * hi];
      bf16x8 vb = *(const bf16x8*)&vr[16 + 8 * hi];
      f32x16& ot = (t == 0 ? o0 : (t == 1 ? o1 : o2));
      ot = __builtin_amdgcn_mfma_f32_32x32x16_bf16(va, fA, ot, 0, 0, 0);
      ot = __builtin_amdgcn_mfma_f32_32x32x16_bf16(vb, fB, ot, 0, 0, 0);
    }
  }

  // write raw partial O^T (combine kernel normalizes)
  const int q = qbase + lo;
  PT* po = part + ((size_t)(bh * 2 + sidx) * AMB) * Nn;
#pragma unroll
  for (int r = 0; r < 16; ++r) {
    const int dr = (r & 3) + 8 * (r >> 2) + 4 * hi;
    pstore(&po[(size_t)dr * Nn + q],        o0[r]);
    pstore(&po[(size_t)(32 + dr) * Nn + q], o1[r]);
  }
  if (hi == 0) pstore(&po[(size_t)64 * Nn + q], o2[0]);
}

// ---------------------------------------------------------------------------
// Combine K-splits + per-head Lorentz normalize -> midN [bh][65][n] f32
// ---------------------------------------------------------------------------
template <bool BF>
__global__ __launch_bounds__(256) void combine_k(const void* __restrict__ partv,
                                                 float* __restrict__ midN) {
  typedef typename PSel<BF>::T PT;
  const PT* part = (const PT*)partv;
  const int g = blockIdx.x * 256 + threadIdx.x;   // 0..65535 = bh*2048+n
  const int bh = g >> 11, n = g & 2047;
  const PT* p0 = part + ((size_t)(bh * 2 + 0) * AMB) * Nn + n;
  const PT* p1 = part + ((size_t)(bh * 2 + 1) * AMB) * Nn + n;
  float Oh[AMB];
#pragma unroll
  for (int d = 0; d < AMB; ++d)
    Oh[d] = pload(&p0[(size_t)d * Nn]) + pload(&p1[(size_t)d * Nn]);
  float ss = 0.f;
#pragma unroll
  for (int d = 0; d < 64; ++d) ss += Oh[d] * Oh[d];
  const float tm  = Oh[64];
  const float inv = rsqrtf(fmaxf(tm * tm - ss, 1e-7f));
  float* mo = midN + (size_t)bh * AMB * Nn + n;
#pragma unroll
  for (int d = 0; d < AMB; ++d) mo[(size_t)d * Nn] = Oh[d] * inv;
}

// ---------------------------------------------------------------------------
// Head-sum (mean absorbed by normalize), normalize, re-lift (C=1)
// ---------------------------------------------------------------------------
__global__ __launch_bounds__(256) void final_k(const float* __restrict__ midN,
                                               float* __restrict__ out) {
  const int g = blockIdx.x * 256 + threadIdx.x;   // 0..8191 = b*2048+n
  const int b = g >> 11, n = g & 2047;
  float sum[AMB];
#pragma unroll
  for (int d = 0; d < AMB; ++d) sum[d] = 0.f;
  for (int h = 0; h < 8; ++h) {
    const float* m = midN + (size_t)(b * 8 + h) * AMB * Nn + n;
#pragma unroll
    for (int d = 0; d < AMB; ++d) sum[d] += m[(size_t)d * Nn];
  }
  float ss = 0.f;
#pragma unroll
  for (int d = 0; d < 64; ++d) ss += sum[d] * sum[d];
  const float tm  = sum[64];
  const float inv = rsqrtf(fmaxf(tm * tm - ss, 1e-7f));
  const float ssp = ss * inv * inv;
  float* o = out + (size_t)g * AMB;
  o[0] = sqrtf(1.0f + ssp);
#pragma unroll
  for (int d = 0; d < 64; ++d) o[1 + d] = sum[d] * inv;
}

// ---------------------------------------------------------------------------
extern "C" void kernel_launch(void* const* d_in, const int* in_sizes, int n_in,
                              void* d_out, int out_size, void* d_ws, size_t ws_size,
                              hipStream_t stream) {
  (void)in_sizes; (void)n_in; (void)out_size;
  const float* x  = (const float*)d_in[0];
  const float* Wq = (const float*)d_in[1];
  const float* Wk = (const float*)d_in[2];
  const float* Wv = (const float*)d_in[3];
  const float* bq = (const float*)d_in[4];
  const float* bk = (const float*)d_in[5];
  const float* bv = (const float*)d_in[6];
  const float* sc = (const float*)d_in[7];
  // d_in[8] = attn_bias: uniform additive score offset -> softmax-invariant.

  char* ws = (char*)d_ws;
  u16*  Qb = (u16*)(ws);                  // 10,485,760 B
  u16*  Kb = (u16*)(ws + 10485760);       // 10,485,760 B
  u16*  Vt = (u16*)(ws + 20971520);       // 12,582,912 B
  void* pb = (void*)(ws + 33554432);      // partials: f32 34,078,720 / bf16 17,039,360
  float* midN = (float*)ws;               // 17,039,360 B (overlays Qb+Kb, dead by then)
  float* out  = (float*)d_out;

  const bool f32p = ws_size >= 67633152ull;   // else bf16 partials (proven 50.6 MB footprint)

  hipLaunchKernelGGL(proj_k, dim3(64, 24), dim3(256), 0, stream,
                     x, Wq, Wk, Wv, bq, bk, bv, sc, Qb, Kb, Vt);
  if (f32p) {
    hipLaunchKernelGGL((attn_k<false>), dim3(16, 32, 2), dim3(256), 0, stream, Qb, Kb, Vt, pb);
    hipLaunchKernelGGL((combine_k<false>), dim3(256), dim3(256), 0, stream, pb, midN);
  } else {
    hipLaunchKernelGGL((attn_k<true>), dim3(16, 32, 2), dim3(256), 0, stream, Qb, Kb, Vt, pb);
    hipLaunchKernelGGL((combine_k<true>), dim3(256), dim3(256), 0, stream, pb, midN);
  }
  hipLaunchKernelGGL(final_k, dim3(32), dim3(256), 0, stream, midN, out);
}

// Round 4
// 212.770 us; speedup vs baseline: 1.4512x; 1.4356x over previous
//
#include <hip/hip_runtime.h>
#include <hip/hip_bf16.h>

typedef __bf16 bf16x8 __attribute__((ext_vector_type(8)));
typedef float f32x16 __attribute__((ext_vector_type(16)));
typedef unsigned int u32;
typedef unsigned short u16;
typedef u32 u32x4 __attribute__((ext_vector_type(4)));

static constexpr int Nn  = 2048;
static constexpr int DIN = 129;   // in_features = D_IN+1
static constexpr int DO  = 64;    // D_OUT
static constexpr int QP  = 80;    // padded q/k width (65 -> 80)
static constexpr int VR  = 96;    // padded V^T rows (65 -> 96)
static constexpr int AMB = 65;    // ambient dim
static constexpr int XP  = 144;   // padded x row (129 -> 144)
static constexpr int NS  = 4;     // K-splits
static constexpr float LOG2E = 1.4426950408889634f;

#define DEV static __device__ __forceinline__

DEV u16 f2bf(float f) {
  union { __bf16 h; u16 u; } c;
  c.h = (__bf16)f;
  return c.u;
}
DEV float bf2f(u16 u) {
  union { float f; u32 uu; } c;
  c.uu = ((u32)u) << 16;
  return c.f;
}
DEV u32 pack2(float a, float b) {
  return (u32)f2bf(a) | ((u32)f2bf(b) << 16);
}

template <bool BF> struct PSel { typedef float T; };
template <> struct PSel<true> { typedef u16 T; };
DEV void pstore(float* p, float v) { *p = v; }
DEV void pstore(u16* p, float v) { *p = f2bf(v); }
DEV float pload(const float* p) { return *p; }
DEV float pload(const u16* p) { return bf2f(*p); }

// ---------------------------------------------------------------------------
// Prep: x (f32 [8192][129]) -> xb (bf16 [8192][144], zero-padded, 16B-aligned)
// ---------------------------------------------------------------------------
__global__ __launch_bounds__(256) void prep_k(const float* __restrict__ x,
                                              u16* __restrict__ xb) {
  const int t = blockIdx.x * 256 + threadIdx.x;   // 0 .. 8192*18-1
  const int row = t / 18, cg = t % 18;
  u16 tmp[8];
#pragma unroll
  for (int j = 0; j < 8; ++j) {
    const int c = cg * 8 + j;
    tmp[j] = (c < DIN) ? f2bf(x[(size_t)row * DIN + c]) : (u16)0;
  }
  u32x4 w;
  w[0] = (u32)tmp[0] | ((u32)tmp[1] << 16);
  w[1] = (u32)tmp[2] | ((u32)tmp[3] << 16);
  w[2] = (u32)tmp[4] | ((u32)tmp[5] << 16);
  w[3] = (u32)tmp[6] | ((u32)tmp[7] << 16);
  *((u32x4*)xb + t) = w;
}

// ---------------------------------------------------------------------------
// Projection: s = xb @ W[h] + b, lift to hyperboloid (C_ATTN=1), store
//   Qb: [bh][n][80] bf16 = alpha' * [qs(64), q0], alpha' = 2*log2e/(scale+eps)
//   Kb: [bh][n][80] bf16 = [ks(64), -(k0-1)]     (centered time: softmax-inv)
//   Vt: [bh][96][n] bf16 = rows 0-63 vs, row 64 v0, rows 65-95 zero
// LDS: W^T only (19.5 KB -> 8 blocks/CU). A-frags straight from xb.
// ---------------------------------------------------------------------------
__global__ __launch_bounds__(256) void proj_k(
    const u16* __restrict__ xb,
    const float* __restrict__ Wq, const float* __restrict__ Wk, const float* __restrict__ Wv,
    const float* __restrict__ bq, const float* __restrict__ bk, const float* __restrict__ bv,
    const float* __restrict__ scale_p,
    u16* __restrict__ Qb, u16* __restrict__ Kb, u16* __restrict__ Vt) {
  __shared__ u16 wt[64][152];       // W^T: [d][k]

  const int tid = threadIdx.x;
  const int wid = tid >> 6, l = tid & 63;
  const int z = blockIdx.y;            // 0..23
  const int T = z >> 3, h = z & 7;     // tensor (0=Q,1=K,2=V), head
  const float* W    = (T == 0 ? Wq : (T == 1 ? Wk : Wv)) + (size_t)h * DIN * DO;
  const float* bias = (T == 0 ? bq : (T == 1 ? bk : bv)) + h * DO;

  {
    const int d = tid & 63, kk = tid >> 6;
    for (int k = kk; k < XP; k += 4)
      wt[d][k] = (k < DIN) ? f2bf(W[(size_t)k * DO + d]) : (u16)0;
  }
  __syncthreads();

  const int lo = l & 31, hi = l >> 5;
  const int row0 = (blockIdx.x * 4 + wid) * 32;
  const u16* xr = xb + (size_t)(row0 + lo) * XP;

  f32x16 acc0 = {}, acc1 = {};
#pragma unroll
  for (int s = 0; s < 9; ++s) {
    bf16x8 a  = *(const bf16x8*)&xr[16 * s + 8 * hi];
    bf16x8 b0 = *(const bf16x8*)&wt[lo][16 * s + 8 * hi];
    bf16x8 b1 = *(const bf16x8*)&wt[32 + lo][16 * s + 8 * hi];
    acc0 = __builtin_amdgcn_mfma_f32_32x32x16_bf16(a, b0, acc0, 0, 0, 0);
    acc1 = __builtin_amdgcn_mfma_f32_32x32x16_bf16(a, b1, acc1, 0, 0, 0);
  }
  const float b0v = bias[lo], b1v = bias[32 + lo];
  const float alpha = 2.0f * LOG2E / (scale_p[0] + 1e-7f);

#pragma unroll
  for (int r = 0; r < 16; ++r) {
    const float s0 = acc0[r] + b0v;
    const float s1 = acc1[r] + b1v;
    float part = s0 * s0 + s1 * s1;
#pragma unroll
    for (int m = 1; m < 32; m <<= 1) part += __shfl_xor(part, m);
    const float time = sqrtf(1.0f + part);     // 1/C_ATTN = 1
    const int dr   = (r & 3) + 8 * (r >> 2) + 4 * hi;
    const int rowg = row0 + dr;
    const int b = rowg >> 11, n = rowg & 2047;
    const int bh = b * 8 + h;
    if (T == 0) {
      u16* q = Qb + ((size_t)bh * Nn + n) * QP;
      q[lo]      = f2bf(alpha * s0);
      q[32 + lo] = f2bf(alpha * s1);
      if (lo == 0)  q[64] = f2bf(alpha * time);
      if (lo < 15)  q[65 + lo] = 0;
    } else if (T == 1) {
      u16* k = Kb + ((size_t)bh * Nn + n) * QP;
      k[lo]      = f2bf(s0);
      k[32 + lo] = f2bf(s1);
      if (lo == 0)  k[64] = f2bf(-(time - 1.0f));
      if (lo < 15)  k[65 + lo] = 0;
    } else {
      u16* v = Vt + (size_t)bh * VR * Nn;
      v[(size_t)lo * Nn + n]        = f2bf(s0);
      v[(size_t)(32 + lo) * Nn + n] = f2bf(s1);
      if (lo == 0) v[(size_t)64 * Nn + n] = f2bf(time);
      if (lo > 0)  v[(size_t)(64 + lo) * Nn + n] = 0;
    }
  }
}

// ---------------------------------------------------------------------------
// Attention (no-max softmax: bounded scores, exp2 direct, scale-invariant
// normalize -> no denominator / rescale / cross-tile state).
// 1 wave = 32 q, swapped QK^T. 1D grid, XCD-chunked swizzle: each XCD owns
// 4 bh (K/V/Q L2-resident). S=4 K-splits; partials part[bh*4+s][65][n].
// ---------------------------------------------------------------------------
template <bool BF>
__global__ __launch_bounds__(256, 4) void attn_k(
    const u16* __restrict__ Qb, const u16* __restrict__ Kb,
    const u16* __restrict__ Vt, void* __restrict__ partv) {
  typedef typename PSel<BF>::T PT;
  PT* part = (PT*)partv;
  const int tid  = threadIdx.x;
  const int w    = tid >> 6, lane = tid & 63;
  const int lo   = lane & 31, hi = lane >> 5;

  // XCD-chunked swizzle (2048 blocks, 8 XCDs, bijective): chunk of 256
  // consecutive swz per XCD -> 4 whole bh per XCD.
  const u32 bid = blockIdx.x;
  const u32 swz = (bid & 7) * 256 + (bid >> 3);
  const int bh   = swz >> 6;
  const int sidx = (swz >> 4) & 3;
  const int qt   = swz & 15;
  const int qbase = qt * 128 + w * 32;

  const u16* qrow = Qb + ((size_t)bh * Nn + qbase + lo) * QP;
  bf16x8 qf[5];
#pragma unroll
  for (int s = 0; s < 5; ++s) qf[s] = *(const bf16x8*)&qrow[16 * s + 8 * hi];

  f32x16 o0 = {}, o1 = {}, o2 = {};   // O^T rows d = 0..31, 32..63, 64..95
  const u16* kb_p = Kb + (size_t)bh * Nn * QP;
  const u16* vb_p = Vt + (size_t)bh * VR * Nn;
  const int k0i = sidx * (Nn / NS), k1i = k0i + (Nn / NS);

  for (int kb = k0i; kb < k1i; kb += 32) {
    // QK^T: D[key][q]
    const u16* krow = kb_p + (size_t)(kb + lo) * QP;
    f32x16 sc = {};
#pragma unroll
    for (int s = 0; s < 5; ++s) {
      bf16x8 kf = *(const bf16x8*)&krow[16 * s + 8 * hi];
      sc = __builtin_amdgcn_mfma_f32_32x32x16_bf16(kf, qf[s], sc, 0, 0, 0);
    }
    // p = 2^score (log2e folded into Q's alpha); no max, no denominator
    float p[16];
#pragma unroll
    for (int r = 0; r < 16; ++r) p[r] = exp2f(sc[r]);

    // P -> bf16 B-fragments. Own keys: crow(r,hi) = (r&3)+8*(r>>2)+4*hi.
    // Fragment needs keys k = 8*hi + j; partner (lane^32) holds the other 8.
    u32 wA[4], wB[4];
#pragma unroll
    for (int j = 0; j < 4; ++j) {
      wA[j] = pack2(p[2 * j], p[2 * j + 1]);
      wB[j] = pack2(p[8 + 2 * j], p[8 + 2 * j + 1]);
    }
    // send-side select: exchange only the 2 words the partner needs
    const u32 sA0 = hi ? wA[0] : wA[2], sA1 = hi ? wA[1] : wA[3];
    const u32 sB0 = hi ? wB[0] : wB[2], sB1 = hi ? wB[1] : wB[3];
    const u32 rA0 = (u32)__shfl_xor((int)sA0, 32);
    const u32 rA1 = (u32)__shfl_xor((int)sA1, 32);
    const u32 rB0 = (u32)__shfl_xor((int)sB0, 32);
    const u32 rB1 = (u32)__shfl_xor((int)sB1, 32);
    u32x4 ua = hi ? (u32x4){rA0, rA1, wA[2], wA[3]}
                  : (u32x4){wA[0], wA[1], rA0, rA1};
    u32x4 ub = hi ? (u32x4){rB0, rB1, wB[2], wB[3]}
                  : (u32x4){wB[0], wB[1], rB0, rB1};
    union { u32x4 u; bf16x8 b; } ca, cb;
    ca.u = ua; cb.u = ub;
    const bf16x8 fA = ca.b;   // keys kb+0..15
    const bf16x8 fB = cb.b;   // keys kb+16..31

    // PV: O^T[d][q] += V^T[d][key] * P^T[key][q]
#pragma unroll
    for (int t = 0; t < 3; ++t) {
      const u16* vr = vb_p + (size_t)(32 * t + lo) * Nn + kb;
      bf16x8 va = *(const bf16x8*)&vr[8 * hi];
      bf16x8 vb = *(const bf16x8*)&vr[16 + 8 * hi];
      f32x16& ot = (t == 0 ? o0 : (t == 1 ? o1 : o2));
      ot = __builtin_amdgcn_mfma_f32_32x32x16_bf16(va, fA, ot, 0, 0, 0);
      ot = __builtin_amdgcn_mfma_f32_32x32x16_bf16(vb, fB, ot, 0, 0, 0);
    }
  }

  // write raw partial O^T (finale normalizes)
  const int q = qbase + lo;
  PT* po = part + ((size_t)(bh * NS + sidx) * AMB) * Nn;
#pragma unroll
  for (int r = 0; r < 16; ++r) {
    const int dr = (r & 3) + 8 * (r >> 2) + 4 * hi;
    pstore(&po[(size_t)dr * Nn + q],        o0[r]);
    pstore(&po[(size_t)(32 + dr) * Nn + q], o1[r]);
  }
  if (hi == 0) pstore(&po[(size_t)64 * Nn + q], o2[0]);
}

// ---------------------------------------------------------------------------
// Finale: combine splits + per-head Lorentz normalize + head-sum + final
// normalize + re-lift (C_ATTN=C_OUT=1). One thread per (b,n) row.
// ---------------------------------------------------------------------------
template <bool BF>
__global__ __launch_bounds__(64) void finale_k(const void* __restrict__ partv,
                                               float* __restrict__ out) {
  typedef typename PSel<BF>::T PT;
  const PT* part = (const PT*)partv;
  const int g = blockIdx.x * 64 + threadIdx.x;    // 0..8191 = b*2048+n
  const int b = g >> 11, n = g & 2047;

  float sum[AMB];
#pragma unroll
  for (int d = 0; d < AMB; ++d) sum[d] = 0.f;

  for (int h = 0; h < 8; ++h) {
    const PT* p0 = part + ((size_t)(b * 8 + h) * NS * AMB) * Nn + n;
    float Oh[AMB];
#pragma unroll
    for (int d = 0; d < AMB; ++d) {
      float v = pload(&p0[(size_t)d * Nn]);
      v += pload(&p0[(size_t)(AMB + d) * Nn]);
      v += pload(&p0[(size_t)(2 * AMB + d) * Nn]);
      v += pload(&p0[(size_t)(3 * AMB + d) * Nn]);
      Oh[d] = v;
    }
    float ss = 0.f;
#pragma unroll
    for (int d = 0; d < 64; ++d) ss += Oh[d] * Oh[d];
    const float tm  = Oh[64];
    const float inv = rsqrtf(fmaxf(tm * tm - ss, 1e-7f));
#pragma unroll
    for (int d = 0; d < AMB; ++d) sum[d] += Oh[d] * inv;
  }

  float ss = 0.f;
#pragma unroll
  for (int d = 0; d < 64; ++d) ss += sum[d] * sum[d];
  const float tm  = sum[64];
  const float inv = rsqrtf(fmaxf(tm * tm - ss, 1e-7f));
  const float ssp = ss * inv * inv;               // ||spatial_out||^2
  float* o = out + (size_t)g * AMB;
  o[0] = sqrtf(1.0f + ssp);
#pragma unroll
  for (int d = 0; d < 64; ++d) o[1 + d] = sum[d] * inv;
}

// ---------------------------------------------------------------------------
extern "C" void kernel_launch(void* const* d_in, const int* in_sizes, int n_in,
                              void* d_out, int out_size, void* d_ws, size_t ws_size,
                              hipStream_t stream) {
  (void)in_sizes; (void)n_in; (void)out_size;
  const float* x  = (const float*)d_in[0];
  const float* Wq = (const float*)d_in[1];
  const float* Wk = (const float*)d_in[2];
  const float* Wv = (const float*)d_in[3];
  const float* bq = (const float*)d_in[4];
  const float* bk = (const float*)d_in[5];
  const float* bv = (const float*)d_in[6];
  const float* sc = (const float*)d_in[7];
  // d_in[8] = attn_bias: uniform additive score offset -> softmax-invariant.

  char* ws = (char*)d_ws;
  u16*  Qb = (u16*)(ws);                  // 10,485,760 B
  u16*  Kb = (u16*)(ws + 10485760);       // 10,485,760 B
  u16*  Vt = (u16*)(ws + 20971520);       // 12,582,912 B
  void* pb = (void*)(ws + 33554432);      // partials: bf16 34 MB / f32 68 MB
  u16*  xb = (u16*)(ws + 33554432);       // 2,359,296 B, dead before attn_k
  float* out = (float*)d_out;

  // f32 partials need 33,554,432 + 68,157,440 = 101,711,872 B
  const bool f32p = ws_size >= 101711872ull;

  hipLaunchKernelGGL(prep_k, dim3(576), dim3(256), 0, stream, x, xb);
  hipLaunchKernelGGL(proj_k, dim3(64, 24), dim3(256), 0, stream,
                     xb, Wq, Wk, Wv, bq, bk, bv, sc, Qb, Kb, Vt);
  if (f32p) {
    hipLaunchKernelGGL((attn_k<false>), dim3(2048), dim3(256), 0, stream, Qb, Kb, Vt, pb);
    hipLaunchKernelGGL((finale_k<false>), dim3(128), dim3(64), 0, stream, pb, out);
  } else {
    hipLaunchKernelGGL((attn_k<true>), dim3(2048), dim3(256), 0, stream, Qb, Kb, Vt, pb);
    hipLaunchKernelGGL((finale_k<true>), dim3(128), dim3(64), 0, stream, pb, out);
  }
}